// Round 1
// baseline (1468.073 us; speedup 1.0000x reference)
//
#include <hip/hip_runtime.h>

// GNN layer: out = segment_sum(nf[src], dst) @ W.T + b
// N=50000 nodes, E=800000 edges, D=128.
// Round 1: baseline = memset + atomic scatter-add into d_out, then in-place
// tiled fp32 linear (W^T staged in LDS, 4x4 register tile per thread).

constexpr int NN = 50000;
constexpr int NE = 800000;
constexpr int D  = 128;

// ---------------- scatter-add: agg[dst] += nf[src] -------------------------
// One thread handles 4 feature dims of one edge: float4 gather + 4 atomics.
__global__ __launch_bounds__(256) void k_scatter(
    const float* __restrict__ nf, const int* __restrict__ ei,
    float* __restrict__ agg)
{
    unsigned t = blockIdx.x * 256u + threadIdx.x;
    unsigned e = t >> 5;            // 32 threads per edge
    if (e >= (unsigned)NE) return;
    unsigned d = (t & 31u) * 4u;
    int s   = ei[e];                // sources are row 0
    int dst = ei[NE + e];           // dests are row 1
    float4 v = *(const float4*)(nf + (size_t)s * D + d);
    float* p = agg + (size_t)dst * D + d;
    atomicAdd(p + 0, v.x);
    atomicAdd(p + 1, v.y);
    atomicAdd(p + 2, v.z);
    atomicAdd(p + 3, v.w);
}

// ---------------- in-place linear: out[i,:] = out[i,:] @ W^T + b -----------
// Tile = 32 rows. Wt[k][j] (stride 132, 16B-aligned, bank-spread) in LDS,
// xs[r][k] (stride 132) in LDS. Thread computes 4 rows x 4 cols.
constexpr int TR = 32;    // rows per tile
constexpr int WS = 132;   // Wt row stride (pad: breaks (j%32) bank pattern, keeps 16B align)
constexpr int XS = 132;   // xs row stride

__global__ __launch_bounds__(256) void k_linear(
    float* __restrict__ out, const float* __restrict__ W,
    const float* __restrict__ b)
{
    __shared__ float Wt[128 * WS];    // Wt[k*WS + j] = W[j*128 + k]
    __shared__ float xs[TR * XS];     // xs[r*XS + k]
    __shared__ float bs[128];

    // Stage W transposed (once per block). Global read coalesced; LDS store
    // hits (4k+j)%32 -> 8-way conflict, but only 64 stores/thread once.
    for (int i = threadIdx.x; i < 128 * 128; i += 256) {
        int j = i >> 7, k = i & 127;
        Wt[k * WS + j] = W[i];
    }
    if (threadIdx.x < 128) bs[threadIdx.x] = b[threadIdx.x];

    const int j4 = (threadIdx.x & 31) * 4;        // 4 output cols
    const int r4 = (threadIdx.x >> 5) * 4;        // 4 rows within tile
    const int ntiles = (NN + TR - 1) / TR;        // 1563 (last tile: 16 rows)

    for (int tile = blockIdx.x; tile < ntiles; tile += gridDim.x) {
        const int row0 = tile * TR;
        __syncthreads();   // xs reuse barrier (also covers Wt on first iter)
        // load 32 rows x 128 cols = 1024 float4, 4 per thread, coalesced
        for (int f = threadIdx.x; f < TR * 32; f += 256) {
            int r = f >> 5, c4 = (f & 31) * 4;
            float4 v;
            if (row0 + r < NN)
                v = *(const float4*)(out + (size_t)(row0 + r) * D + c4);
            else
                v = make_float4(0.f, 0.f, 0.f, 0.f);
            *(float4*)(xs + r * XS + c4) = v;
        }
        __syncthreads();

        float acc[4][4];
        #pragma unroll
        for (int a = 0; a < 4; ++a)
            #pragma unroll
            for (int c = 0; c < 4; ++c)
                acc[a][c] = bs[j4 + c];

        #pragma unroll 4
        for (int k = 0; k < 128; ++k) {
            float4 w = *(const float4*)(Wt + k * WS + j4);   // b128, conflict-free
            float x0 = xs[(r4 + 0) * XS + k];                // half-wave broadcast
            float x1 = xs[(r4 + 1) * XS + k];
            float x2 = xs[(r4 + 2) * XS + k];
            float x3 = xs[(r4 + 3) * XS + k];
            acc[0][0] += x0 * w.x; acc[0][1] += x0 * w.y; acc[0][2] += x0 * w.z; acc[0][3] += x0 * w.w;
            acc[1][0] += x1 * w.x; acc[1][1] += x1 * w.y; acc[1][2] += x1 * w.z; acc[1][3] += x1 * w.w;
            acc[2][0] += x2 * w.x; acc[2][1] += x2 * w.y; acc[2][2] += x2 * w.z; acc[2][3] += x2 * w.w;
            acc[3][0] += x3 * w.x; acc[3][1] += x3 * w.y; acc[3][2] += x3 * w.z; acc[3][3] += x3 * w.w;
        }

        #pragma unroll
        for (int a = 0; a < 4; ++a) {
            int r = row0 + r4 + a;
            if (r < NN) {
                *(float4*)(out + (size_t)r * D + j4) =
                    make_float4(acc[a][0], acc[a][1], acc[a][2], acc[a][3]);
            }
        }
    }
}

extern "C" void kernel_launch(void* const* d_in, const int* in_sizes, int n_in,
                              void* d_out, int out_size, void* d_ws, size_t ws_size,
                              hipStream_t stream) {
    const float* nf = (const float*)d_in[0];
    const int*   ei = (const int*)d_in[1];   // int32 (JAX x64 disabled)
    const float* W  = (const float*)d_in[2];
    const float* b  = (const float*)d_in[3];
    float* out = (float*)d_out;

    hipMemsetAsync(out, 0, (size_t)NN * D * sizeof(float), stream);

    // scatter: 800000 edges * 32 threads = 25.6M threads
    k_scatter<<<(NE * 32) / 256, 256, 0, stream>>>(nf, ei, out);

    // in-place linear: 83 KB LDS -> 1 block/CU; 512 blocks grid-stride
    k_linear<<<512, 256, 0, stream>>>(out, W, b);
}

// Round 2
// 291.724 us; speedup vs baseline: 5.0324x; 5.0324x over previous
//
#include <hip/hip_runtime.h>

// GNN layer: out = segment_sum(nf[src], dst) @ W.T + b
// N=50000, E=800000, D=128.
// Round 2: replace 102.4M fp32 atomics (R1: 1342us, WRITE_SIZE 1.6GB) with
// CSR counting-sort + one-wave-per-node register aggregation (writes each
// output row once). Linear kernel unchanged from R1 (verified correct).

constexpr int NN = 50000;
constexpr int NE = 800000;
constexpr int D  = 128;

constexpr int SCAN_CHUNK = 1024;                       // elems per scan block
constexpr int NSCAN = (NN + SCAN_CHUNK - 1) / SCAN_CHUNK;   // 49

// ---- 1. histogram of destinations ----------------------------------------
__global__ __launch_bounds__(256) void k_hist(const int* __restrict__ ei,
                                              int* __restrict__ deg) {
    int e = blockIdx.x * 256 + threadIdx.x;
    if (e < NE) atomicAdd(&deg[ei[NE + e]], 1);
}

// ---- 2a. per-block partial sums (1024 elems / block) ----------------------
__global__ __launch_bounds__(256) void k_blocksum(const int* __restrict__ deg,
                                                  int* __restrict__ blocksum) {
    __shared__ int s[256];
    int t = threadIdx.x, b = blockIdx.x;
    int v = 0;
    int i0 = b * SCAN_CHUNK + t * 4;
    #pragma unroll
    for (int j = 0; j < 4; ++j) {
        int i = i0 + j;
        if (i < NN) v += deg[i];
    }
    s[t] = v; __syncthreads();
    for (int off = 128; off > 0; off >>= 1) {
        if (t < off) s[t] += s[t + off];
        __syncthreads();
    }
    if (t == 0) blocksum[b] = s[0];
}

// ---- 2b. exclusive scan of the 49 block sums (single thread, trivial) -----
__global__ void k_scanblk(const int* __restrict__ blocksum,
                          int* __restrict__ blockoff) {
    if (threadIdx.x == 0 && blockIdx.x == 0) {
        int run = 0;
        for (int b = 0; b < NSCAN; ++b) { blockoff[b] = run; run += blocksum[b]; }
    }
}

// ---- 2c. final scan: offsets[i] = exclusive prefix of deg; cursor copy ----
__global__ __launch_bounds__(256) void k_scanfinal(const int* __restrict__ deg,
                                                   const int* __restrict__ blockoff,
                                                   int* __restrict__ offsets,
                                                   int* __restrict__ cursor) {
    __shared__ int s[256];
    int t = threadIdx.x, b = blockIdx.x;
    int i0 = b * SCAN_CHUNK + t * 4;
    int loc[4]; int tsum = 0;
    #pragma unroll
    for (int j = 0; j < 4; ++j) {
        int i = i0 + j;
        loc[j] = (i < NN) ? deg[i] : 0;
        tsum += loc[j];
    }
    s[t] = tsum; __syncthreads();
    for (int off = 1; off < 256; off <<= 1) {
        int v = (t >= off) ? s[t - off] : 0;
        __syncthreads();
        s[t] += v;
        __syncthreads();
    }
    int pre = blockoff[b] + s[t] - tsum;   // exclusive prefix for this thread
    #pragma unroll
    for (int j = 0; j < 4; ++j) {
        int i = i0 + j;
        if (i < NN) { offsets[i] = pre; cursor[i] = pre; }
        pre += loc[j];
    }
    if (b == 0 && t == 0) offsets[NN] = NE;   // total is statically known
}

// ---- 3. scatter edge sources into CSR order -------------------------------
__global__ __launch_bounds__(256) void k_scatter_idx(const int* __restrict__ ei,
                                                     int* __restrict__ cursor,
                                                     int* __restrict__ sorted_src) {
    int e = blockIdx.x * 256 + threadIdx.x;
    if (e >= NE) return;
    int dst = ei[NE + e];
    int pos = atomicAdd(&cursor[dst], 1);
    sorted_src[pos] = ei[e];
}

// ---- 4. aggregate: one wave per node, float2/lane, register accumulate ----
__global__ __launch_bounds__(256) void k_aggregate(const float* __restrict__ nf,
                                                   const int* __restrict__ sorted_src,
                                                   const int* __restrict__ offsets,
                                                   float* __restrict__ out) {
    int wv   = (blockIdx.x * 256 + threadIdx.x) >> 6;   // node id
    int lane = threadIdx.x & 63;
    if (wv >= NN) return;
    int beg = offsets[wv], end = offsets[wv + 1];
    const float* base = nf + 2 * lane;
    float ax = 0.f, ay = 0.f, bx = 0.f, by = 0.f;
    int i = beg;
    for (; i + 1 < end; i += 2) {          // 2-way unroll for MLP
        int s0 = sorted_src[i];
        int s1 = sorted_src[i + 1];
        float2 v0 = *(const float2*)(base + (size_t)s0 * D);
        float2 v1 = *(const float2*)(base + (size_t)s1 * D);
        ax += v0.x; ay += v0.y;
        bx += v1.x; by += v1.y;
    }
    if (i < end) {
        int s0 = sorted_src[i];
        float2 v0 = *(const float2*)(base + (size_t)s0 * D);
        ax += v0.x; ay += v0.y;
    }
    float2 r; r.x = ax + bx; r.y = ay + by;
    *(float2*)(out + (size_t)wv * D + 2 * lane) = r;
}

// ---- 5. in-place linear: out[i,:] = out[i,:] @ W^T + b (from R1) ----------
constexpr int TR = 32;
constexpr int WS = 132;
constexpr int XS = 132;

__global__ __launch_bounds__(256) void k_linear(
    float* __restrict__ out, const float* __restrict__ W,
    const float* __restrict__ b)
{
    __shared__ float Wt[128 * WS];
    __shared__ float xs[TR * XS];
    __shared__ float bs[128];

    for (int i = threadIdx.x; i < 128 * 128; i += 256) {
        int j = i >> 7, k = i & 127;
        Wt[k * WS + j] = W[i];
    }
    if (threadIdx.x < 128) bs[threadIdx.x] = b[threadIdx.x];

    const int j4 = (threadIdx.x & 31) * 4;
    const int r4 = (threadIdx.x >> 5) * 4;
    const int ntiles = (NN + TR - 1) / TR;

    for (int tile = blockIdx.x; tile < ntiles; tile += gridDim.x) {
        const int row0 = tile * TR;
        __syncthreads();
        for (int f = threadIdx.x; f < TR * 32; f += 256) {
            int r = f >> 5, c4 = (f & 31) * 4;
            float4 v;
            if (row0 + r < NN)
                v = *(const float4*)(out + (size_t)(row0 + r) * D + c4);
            else
                v = make_float4(0.f, 0.f, 0.f, 0.f);
            *(float4*)(xs + r * XS + c4) = v;
        }
        __syncthreads();

        float acc[4][4];
        #pragma unroll
        for (int a = 0; a < 4; ++a)
            #pragma unroll
            for (int c = 0; c < 4; ++c)
                acc[a][c] = bs[j4 + c];

        #pragma unroll 4
        for (int k = 0; k < 128; ++k) {
            float4 w = *(const float4*)(Wt + k * WS + j4);
            float x0 = xs[(r4 + 0) * XS + k];
            float x1 = xs[(r4 + 1) * XS + k];
            float x2 = xs[(r4 + 2) * XS + k];
            float x3 = xs[(r4 + 3) * XS + k];
            acc[0][0] += x0 * w.x; acc[0][1] += x0 * w.y; acc[0][2] += x0 * w.z; acc[0][3] += x0 * w.w;
            acc[1][0] += x1 * w.x; acc[1][1] += x1 * w.y; acc[1][2] += x1 * w.z; acc[1][3] += x1 * w.w;
            acc[2][0] += x2 * w.x; acc[2][1] += x2 * w.y; acc[2][2] += x2 * w.z; acc[2][3] += x2 * w.w;
            acc[3][0] += x3 * w.x; acc[3][1] += x3 * w.y; acc[3][2] += x3 * w.z; acc[3][3] += x3 * w.w;
        }

        #pragma unroll
        for (int a = 0; a < 4; ++a) {
            int r = row0 + r4 + a;
            if (r < NN) {
                *(float4*)(out + (size_t)r * D + j4) =
                    make_float4(acc[a][0], acc[a][1], acc[a][2], acc[a][3]);
            }
        }
    }
}

extern "C" void kernel_launch(void* const* d_in, const int* in_sizes, int n_in,
                              void* d_out, int out_size, void* d_ws, size_t ws_size,
                              hipStream_t stream) {
    const float* nf = (const float*)d_in[0];
    const int*   ei = (const int*)d_in[1];
    const float* W  = (const float*)d_in[2];
    const float* b  = (const float*)d_in[3];
    float* out = (float*)d_out;

    // workspace layout (ints): ~4.0 MB total
    int* deg      = (int*)d_ws;          // NN
    int* offsets  = deg + NN;            // NN+1
    int* cursor   = offsets + NN + 1;    // NN
    int* blocksum = cursor + NN;         // 64
    int* blockoff = blocksum + 64;       // 64
    int* sorted   = blockoff + 64;       // NE

    hipMemsetAsync(deg, 0, NN * sizeof(int), stream);

    k_hist       <<<(NE + 255) / 256, 256, 0, stream>>>(ei, deg);
    k_blocksum   <<<NSCAN, 256, 0, stream>>>(deg, blocksum);
    k_scanblk    <<<1, 64, 0, stream>>>(blocksum, blockoff);
    k_scanfinal  <<<NSCAN, 256, 0, stream>>>(deg, blockoff, offsets, cursor);
    k_scatter_idx<<<(NE + 255) / 256, 256, 0, stream>>>(ei, cursor, sorted);

    // one wave per node: 50000 waves = 12500 blocks of 256
    k_aggregate  <<<(NN * 64 + 255) / 256, 256, 0, stream>>>(nf, sorted, offsets, out);

    k_linear     <<<512, 256, 0, stream>>>(out, W, b);
}

// Round 3
// 266.957 us; speedup vs baseline: 5.4993x; 1.0928x over previous
//
#include <hip/hip_runtime.h>

// GNN layer: out = segment_sum(nf[src], dst) @ W.T + b
// N=50000, E=800000, D=128.
// R3: bf16-convert node features once (halves gather traffic, 25.6->12.8MB
// working set), CSR aggregate with unroll-4 dword gathers (4 edges in
// flight), scan pipeline merged to 2 kernels. Linear unchanged (R1-verified).

constexpr int NN = 50000;
constexpr int NE = 800000;
constexpr int D  = 128;

constexpr int SCAN_CHUNK = 1024;
constexpr int NSCAN = (NN + SCAN_CHUNK - 1) / SCAN_CHUNK;   // 49

// ---- 0. fp32 -> bf16 (RNE) conversion of node features -------------------
__device__ inline unsigned short f2bf(float f) {
    unsigned u = __float_as_uint(f);
    return (unsigned short)((u + 0x7fffu + ((u >> 16) & 1u)) >> 16);
}

__global__ __launch_bounds__(256) void k_cvt(const float* __restrict__ nf,
                                             ushort* __restrict__ nfh) {
    int t = blockIdx.x * 256 + threadIdx.x;
    if (t >= NN * D / 4) return;
    float4 v = ((const float4*)nf)[t];
    ushort4 o;
    o.x = f2bf(v.x); o.y = f2bf(v.y); o.z = f2bf(v.z); o.w = f2bf(v.w);
    ((ushort4*)nfh)[t] = o;
}

// ---- 1. histogram of destinations ----------------------------------------
__global__ __launch_bounds__(256) void k_hist(const int* __restrict__ ei,
                                              int* __restrict__ deg) {
    int e = blockIdx.x * 256 + threadIdx.x;
    if (e < NE) atomicAdd(&deg[ei[NE + e]], 1);
}

// ---- 2a. per-block partial sums (1024 elems / block) ----------------------
__global__ __launch_bounds__(256) void k_blocksum(const int* __restrict__ deg,
                                                  int* __restrict__ blocksum) {
    __shared__ int s[256];
    int t = threadIdx.x, b = blockIdx.x;
    int v = 0;
    int i0 = b * SCAN_CHUNK + t * 4;
    #pragma unroll
    for (int j = 0; j < 4; ++j) {
        int i = i0 + j;
        if (i < NN) v += deg[i];
    }
    s[t] = v; __syncthreads();
    for (int off = 128; off > 0; off >>= 1) {
        if (t < off) s[t] += s[t + off];
        __syncthreads();
    }
    if (t == 0) blocksum[b] = s[0];
}

// ---- 2b. final scan (merged: each block redundantly scans block sums) -----
__global__ __launch_bounds__(256) void k_scanfinal(const int* __restrict__ deg,
                                                   const int* __restrict__ blocksum,
                                                   int* __restrict__ offsets,
                                                   int* __restrict__ cursor) {
    __shared__ int s[256];
    __shared__ int sblk[NSCAN];
    __shared__ int myblkoff;
    int t = threadIdx.x, b = blockIdx.x;
    if (t < NSCAN) sblk[t] = blocksum[t];
    __syncthreads();
    if (t == 0) {                       // serial exclusive scan of 49 sums
        int run = 0;
        for (int i = 0; i < NSCAN; ++i) {
            if (i == b) myblkoff = run;
            run += sblk[i];
        }
    }
    int i0 = b * SCAN_CHUNK + t * 4;
    int loc[4]; int tsum = 0;
    #pragma unroll
    for (int j = 0; j < 4; ++j) {
        int i = i0 + j;
        loc[j] = (i < NN) ? deg[i] : 0;
        tsum += loc[j];
    }
    s[t] = tsum; __syncthreads();
    for (int off = 1; off < 256; off <<= 1) {
        int v = (t >= off) ? s[t - off] : 0;
        __syncthreads();
        s[t] += v;
        __syncthreads();
    }
    int pre = myblkoff + s[t] - tsum;
    #pragma unroll
    for (int j = 0; j < 4; ++j) {
        int i = i0 + j;
        if (i < NN) { offsets[i] = pre; cursor[i] = pre; }
        pre += loc[j];
    }
    if (b == 0 && t == 0) offsets[NN] = NE;
}

// ---- 3. scatter edge sources into CSR order -------------------------------
__global__ __launch_bounds__(256) void k_scatter_idx(const int* __restrict__ ei,
                                                     int* __restrict__ cursor,
                                                     int* __restrict__ sorted_src) {
    int e = blockIdx.x * 256 + threadIdx.x;
    if (e >= NE) return;
    int dst = ei[NE + e];
    int pos = atomicAdd(&cursor[dst], 1);
    sorted_src[pos] = ei[e];
}

// ---- 4. aggregate: one wave per node, bf16 dword/lane, 4 edges in flight --
__device__ inline float bflo(unsigned v) { return __uint_as_float(v << 16); }
__device__ inline float bfhi(unsigned v) { return __uint_as_float(v & 0xffff0000u); }

__global__ __launch_bounds__(256) void k_aggregate(const unsigned* __restrict__ nfh,
                                                   const int* __restrict__ sorted_src,
                                                   const int* __restrict__ offsets,
                                                   float* __restrict__ out) {
    int wv   = (blockIdx.x * 256 + threadIdx.x) >> 6;   // node id
    int lane = threadIdx.x & 63;
    if (wv >= NN) return;
    int beg = offsets[wv], end = offsets[wv + 1];
    float s0x = 0.f, s0y = 0.f, s1x = 0.f, s1y = 0.f;
    float s2x = 0.f, s2y = 0.f, s3x = 0.f, s3y = 0.f;
    int i = beg;
    for (; i + 3 < end; i += 4) {       // 4 independent gathers in flight
        int a = sorted_src[i + 0];
        int b = sorted_src[i + 1];
        int c = sorted_src[i + 2];
        int d = sorted_src[i + 3];
        unsigned v0 = nfh[(size_t)a * 64 + lane];   // 2 bf16 dims / lane
        unsigned v1 = nfh[(size_t)b * 64 + lane];
        unsigned v2 = nfh[(size_t)c * 64 + lane];
        unsigned v3 = nfh[(size_t)d * 64 + lane];
        s0x += bflo(v0); s0y += bfhi(v0);
        s1x += bflo(v1); s1y += bfhi(v1);
        s2x += bflo(v2); s2y += bfhi(v2);
        s3x += bflo(v3); s3y += bfhi(v3);
    }
    for (; i < end; ++i) {
        int a = sorted_src[i];
        unsigned v0 = nfh[(size_t)a * 64 + lane];
        s0x += bflo(v0); s0y += bfhi(v0);
    }
    float2 r;
    r.x = (s0x + s1x) + (s2x + s3x);
    r.y = (s0y + s1y) + (s2y + s3y);
    *(float2*)(out + (size_t)wv * D + 2 * lane) = r;
}

// ---- 5. in-place linear: out[i,:] = out[i,:] @ W^T + b (R1-verified) ------
constexpr int TR = 32;
constexpr int WS = 132;
constexpr int XS = 132;

__global__ __launch_bounds__(256) void k_linear(
    float* __restrict__ out, const float* __restrict__ W,
    const float* __restrict__ b)
{
    __shared__ float Wt[128 * WS];
    __shared__ float xs[TR * XS];
    __shared__ float bs[128];

    for (int i = threadIdx.x; i < 128 * 128; i += 256) {
        int j = i >> 7, k = i & 127;
        Wt[k * WS + j] = W[i];
    }
    if (threadIdx.x < 128) bs[threadIdx.x] = b[threadIdx.x];

    const int j4 = (threadIdx.x & 31) * 4;
    const int r4 = (threadIdx.x >> 5) * 4;
    const int ntiles = (NN + TR - 1) / TR;

    for (int tile = blockIdx.x; tile < ntiles; tile += gridDim.x) {
        const int row0 = tile * TR;
        __syncthreads();
        for (int f = threadIdx.x; f < TR * 32; f += 256) {
            int r = f >> 5, c4 = (f & 31) * 4;
            float4 v;
            if (row0 + r < NN)
                v = *(const float4*)(out + (size_t)(row0 + r) * D + c4);
            else
                v = make_float4(0.f, 0.f, 0.f, 0.f);
            *(float4*)(xs + r * XS + c4) = v;
        }
        __syncthreads();

        float acc[4][4];
        #pragma unroll
        for (int a = 0; a < 4; ++a)
            #pragma unroll
            for (int c = 0; c < 4; ++c)
                acc[a][c] = bs[j4 + c];

        #pragma unroll 4
        for (int k = 0; k < 128; ++k) {
            float4 w = *(const float4*)(Wt + k * WS + j4);
            float x0 = xs[(r4 + 0) * XS + k];
            float x1 = xs[(r4 + 1) * XS + k];
            float x2 = xs[(r4 + 2) * XS + k];
            float x3 = xs[(r4 + 3) * XS + k];
            acc[0][0] += x0 * w.x; acc[0][1] += x0 * w.y; acc[0][2] += x0 * w.z; acc[0][3] += x0 * w.w;
            acc[1][0] += x1 * w.x; acc[1][1] += x1 * w.y; acc[1][2] += x1 * w.z; acc[1][3] += x1 * w.w;
            acc[2][0] += x2 * w.x; acc[2][1] += x2 * w.y; acc[2][2] += x2 * w.z; acc[2][3] += x2 * w.w;
            acc[3][0] += x3 * w.x; acc[3][1] += x3 * w.y; acc[3][2] += x3 * w.z; acc[3][3] += x3 * w.w;
        }

        #pragma unroll
        for (int a = 0; a < 4; ++a) {
            int r = row0 + r4 + a;
            if (r < NN) {
                *(float4*)(out + (size_t)r * D + j4) =
                    make_float4(acc[a][0], acc[a][1], acc[a][2], acc[a][3]);
            }
        }
    }
}

extern "C" void kernel_launch(void* const* d_in, const int* in_sizes, int n_in,
                              void* d_out, int out_size, void* d_ws, size_t ws_size,
                              hipStream_t stream) {
    const float* nf = (const float*)d_in[0];
    const int*   ei = (const int*)d_in[1];
    const float* W  = (const float*)d_in[2];
    const float* b  = (const float*)d_in[3];
    float* out = (float*)d_out;

    // workspace layout: nfh (bf16 features) first, then CSR ints. ~16.6 MB.
    ushort* nfh    = (ushort*)d_ws;              // NN*D bf16 = 12.8 MB
    int* deg       = (int*)(nfh + (size_t)NN * D);  // NN
    int* offsets   = deg + NN;                   // NN+1
    int* cursor    = offsets + NN + 1;           // NN
    int* blocksum  = cursor + NN;                // 64
    int* sorted    = blocksum + 64;              // NE

    hipMemsetAsync(deg, 0, NN * sizeof(int), stream);

    k_cvt        <<<(NN * D / 4 + 255) / 256, 256, 0, stream>>>(nf, nfh);
    k_hist       <<<(NE + 255) / 256, 256, 0, stream>>>(ei, deg);
    k_blocksum   <<<NSCAN, 256, 0, stream>>>(deg, blocksum);
    k_scanfinal  <<<NSCAN, 256, 0, stream>>>(deg, blocksum, offsets, cursor);
    k_scatter_idx<<<(NE + 255) / 256, 256, 0, stream>>>(ei, cursor, sorted);

    k_aggregate  <<<(NN * 64 + 255) / 256, 256, 0, stream>>>((const unsigned*)nfh, sorted, offsets, out);

    k_linear     <<<512, 256, 0, stream>>>(out, W, b);
}

// Round 4
// 235.745 us; speedup vs baseline: 6.2274x; 1.1324x over previous
//
#include <hip/hip_runtime.h>

// GNN layer: out = segment_sum(nf[src], dst) @ W.T + b
// N=50000, E=800000, D=128.
// R4: (a) linear -> LDS-free bf16 MFMA GEMM (R3: fp32 vector, 85KB LDS,
// 8.8% occupancy, 56us); (b) aggregate emits bf16 agg (halves its writes),
// unroll-8 gathers; (c) k_prep fuses nf-cvt + W-cvt + deg-zero (drops memset).

constexpr int NN = 50000;
constexpr int NE = 800000;
constexpr int D  = 128;

constexpr int SCAN_CHUNK = 1024;
constexpr int NSCAN = (NN + SCAN_CHUNK - 1) / SCAN_CHUNK;   // 49

typedef __attribute__((ext_vector_type(8))) short bf16x8;
typedef __attribute__((ext_vector_type(4))) float f32x4;

__device__ inline unsigned short f2bf(float f) {           // RNE
    unsigned u = __float_as_uint(f);
    return (unsigned short)((u + 0x7fffu + ((u >> 16) & 1u)) >> 16);
}
__device__ inline float bflo(unsigned v) { return __uint_as_float(v << 16); }
__device__ inline float bfhi(unsigned v) { return __uint_as_float(v & 0xffff0000u); }

// ---- 0. prep: nf->bf16, W->bf16, deg=0 (one fused elementwise kernel) -----
constexpr int NF4  = NN * D / 4;        // 1,600,000
constexpr int W4   = D * D / 4;         // 4,096
constexpr int DEG4 = NN / 4;            // 12,500
constexpr int PREP_TOT = NF4 + W4 + DEG4;

__global__ __launch_bounds__(256) void k_prep(const float* __restrict__ nf,
                                              const float* __restrict__ W,
                                              ushort* __restrict__ nfh,
                                              ushort* __restrict__ Wh,
                                              int* __restrict__ deg) {
    int t = blockIdx.x * 256 + threadIdx.x;
    if (t < NF4) {
        float4 v = ((const float4*)nf)[t];
        ((ushort4*)nfh)[t] = make_ushort4(f2bf(v.x), f2bf(v.y), f2bf(v.z), f2bf(v.w));
    } else if (t < NF4 + W4) {
        int i = t - NF4;
        float4 v = ((const float4*)W)[i];
        ((ushort4*)Wh)[i] = make_ushort4(f2bf(v.x), f2bf(v.y), f2bf(v.z), f2bf(v.w));
    } else if (t < PREP_TOT) {
        ((int4*)deg)[t - NF4 - W4] = make_int4(0, 0, 0, 0);
    }
}

// ---- 1. histogram of destinations ----------------------------------------
__global__ __launch_bounds__(256) void k_hist(const int* __restrict__ ei,
                                              int* __restrict__ deg) {
    int e = blockIdx.x * 256 + threadIdx.x;
    if (e < NE) atomicAdd(&deg[ei[NE + e]], 1);
}

// ---- 2a. per-block partial sums (1024 elems / block) ----------------------
__global__ __launch_bounds__(256) void k_blocksum(const int* __restrict__ deg,
                                                  int* __restrict__ blocksum) {
    __shared__ int s[256];
    int t = threadIdx.x, b = blockIdx.x;
    int v = 0;
    int i0 = b * SCAN_CHUNK + t * 4;
    #pragma unroll
    for (int j = 0; j < 4; ++j) {
        int i = i0 + j;
        if (i < NN) v += deg[i];
    }
    s[t] = v; __syncthreads();
    for (int off = 128; off > 0; off >>= 1) {
        if (t < off) s[t] += s[t + off];
        __syncthreads();
    }
    if (t == 0) blocksum[b] = s[0];
}

// ---- 2b. final scan (each block redundantly scans the 49 block sums) ------
__global__ __launch_bounds__(256) void k_scanfinal(const int* __restrict__ deg,
                                                   const int* __restrict__ blocksum,
                                                   int* __restrict__ offsets,
                                                   int* __restrict__ cursor) {
    __shared__ int s[256];
    __shared__ int sblk[NSCAN];
    __shared__ int myblkoff;
    int t = threadIdx.x, b = blockIdx.x;
    if (t < NSCAN) sblk[t] = blocksum[t];
    __syncthreads();
    if (t == 0) {
        int run = 0;
        for (int i = 0; i < NSCAN; ++i) {
            if (i == b) myblkoff = run;
            run += sblk[i];
        }
    }
    int i0 = b * SCAN_CHUNK + t * 4;
    int loc[4]; int tsum = 0;
    #pragma unroll
    for (int j = 0; j < 4; ++j) {
        int i = i0 + j;
        loc[j] = (i < NN) ? deg[i] : 0;
        tsum += loc[j];
    }
    s[t] = tsum; __syncthreads();
    for (int off = 1; off < 256; off <<= 1) {
        int v = (t >= off) ? s[t - off] : 0;
        __syncthreads();
        s[t] += v;
        __syncthreads();
    }
    int pre = myblkoff + s[t] - tsum;
    #pragma unroll
    for (int j = 0; j < 4; ++j) {
        int i = i0 + j;
        if (i < NN) { offsets[i] = pre; cursor[i] = pre; }
        pre += loc[j];
    }
    if (b == 0 && t == 0) offsets[NN] = NE;
}

// ---- 3. scatter edge sources into CSR order -------------------------------
__global__ __launch_bounds__(256) void k_scatter_idx(const int* __restrict__ ei,
                                                     int* __restrict__ cursor,
                                                     int* __restrict__ sorted_src) {
    int e = blockIdx.x * 256 + threadIdx.x;
    if (e >= NE) return;
    int dst = ei[NE + e];
    int pos = atomicAdd(&cursor[dst], 1);
    sorted_src[pos] = ei[e];
}

// ---- 4. aggregate: one wave/node, bf16 dword/lane, 8 gathers in flight ----
__global__ __launch_bounds__(256) void k_aggregate(const unsigned* __restrict__ nfh,
                                                   const int* __restrict__ sorted_src,
                                                   const int* __restrict__ offsets,
                                                   unsigned* __restrict__ aggh) {
    int wv   = (blockIdx.x * 256 + threadIdx.x) >> 6;
    int lane = threadIdx.x & 63;
    if (wv >= NN) return;
    int beg = offsets[wv], end = offsets[wv + 1];
    float ax=0.f, ay=0.f, bx=0.f, by=0.f, cx=0.f, cy=0.f, dx=0.f, dy=0.f;
    int i = beg;
    for (; i + 7 < end; i += 8) {
        int e0 = sorted_src[i+0]; int e1 = sorted_src[i+1];
        int e2 = sorted_src[i+2]; int e3 = sorted_src[i+3];
        int e4 = sorted_src[i+4]; int e5 = sorted_src[i+5];
        int e6 = sorted_src[i+6]; int e7 = sorted_src[i+7];
        unsigned v0 = nfh[(size_t)e0 * 64 + lane];
        unsigned v1 = nfh[(size_t)e1 * 64 + lane];
        unsigned v2 = nfh[(size_t)e2 * 64 + lane];
        unsigned v3 = nfh[(size_t)e3 * 64 + lane];
        unsigned v4 = nfh[(size_t)e4 * 64 + lane];
        unsigned v5 = nfh[(size_t)e5 * 64 + lane];
        unsigned v6 = nfh[(size_t)e6 * 64 + lane];
        unsigned v7 = nfh[(size_t)e7 * 64 + lane];
        ax += bflo(v0); ay += bfhi(v0);
        bx += bflo(v1); by += bfhi(v1);
        cx += bflo(v2); cy += bfhi(v2);
        dx += bflo(v3); dy += bfhi(v3);
        ax += bflo(v4); ay += bfhi(v4);
        bx += bflo(v5); by += bfhi(v5);
        cx += bflo(v6); cy += bfhi(v6);
        dx += bflo(v7); dy += bfhi(v7);
    }
    for (; i < end; ++i) {
        unsigned v0 = nfh[(size_t)sorted_src[i] * 64 + lane];
        ax += bflo(v0); ay += bfhi(v0);
    }
    float rx = (ax + bx) + (cx + dx);
    float ry = (ay + by) + (cy + dy);
    aggh[(size_t)wv * 64 + lane] = (unsigned)f2bf(rx) | ((unsigned)f2bf(ry) << 16);
}

// ---- 5. linear: out = aggh @ Wh.T + b  (bf16 MFMA, no LDS) ----------------
// Wave computes 16 rows x 128 cols. A: row=lane&15, k=quad*8+j (16B contig).
// B: col(n)=lane&15 -> W row, same k indexing. D: col=lane&15, row=quad*4+reg.
__global__ __launch_bounds__(256) void k_linear(const ushort* __restrict__ aggh,
                                                const ushort* __restrict__ Wh,
                                                const float* __restrict__ b,
                                                float* __restrict__ out) {
    int wave = threadIdx.x >> 6;
    int lane = threadIdx.x & 63;
    int R = blockIdx.x * 64 + wave * 16;
    if (R >= NN) return;                 // 50000 % 16 == 0: chunks are full
    int m = lane & 15;
    int q = lane >> 4;

    bf16x8 a[4];
    const ushort* arow = aggh + (size_t)(R + m) * D + q * 8;
    #pragma unroll
    for (int kk = 0; kk < 4; ++kk)
        a[kk] = *(const bf16x8*)(arow + kk * 32);

    #pragma unroll
    for (int c0 = 0; c0 < D; c0 += 16) {
        float bias = b[c0 + m];
        f32x4 acc = { bias, bias, bias, bias };
        const ushort* wrow = Wh + (size_t)(c0 + m) * D + q * 8;
        #pragma unroll
        for (int kk = 0; kk < 4; ++kk) {
            bf16x8 bb = *(const bf16x8*)(wrow + kk * 32);
            acc = __builtin_amdgcn_mfma_f32_16x16x32_bf16(a[kk], bb, acc, 0, 0, 0);
        }
        int row = R + q * 4;
        float* op = out + (size_t)row * D + c0 + m;
        op[0]     = acc[0];
        op[D]     = acc[1];
        op[2 * D] = acc[2];
        op[3 * D] = acc[3];
    }
}

extern "C" void kernel_launch(void* const* d_in, const int* in_sizes, int n_in,
                              void* d_out, int out_size, void* d_ws, size_t ws_size,
                              hipStream_t stream) {
    const float* nf = (const float*)d_in[0];
    const int*   ei = (const int*)d_in[1];
    const float* W  = (const float*)d_in[2];
    const float* b  = (const float*)d_in[3];
    float* out = (float*)d_out;

    // workspace layout (~29.5 MB, all 16B-aligned segments)
    ushort* nfh   = (ushort*)d_ws;                      // NN*D bf16 = 12.8 MB
    ushort* Wh    = nfh + (size_t)NN * D;               // 16384 bf16 = 32 KB
    ushort* aggh  = Wh + D * D;                         // NN*D bf16 = 12.8 MB
    int* deg      = (int*)(aggh + (size_t)NN * D);      // NN
    int* offsets  = deg + NN;                           // NN+1
    int* cursor   = offsets + NN + 1;                   // NN
    int* blocksum = cursor + NN;                        // 64
    int* sorted   = blocksum + 64;                      // NE = 3.2 MB

    k_prep       <<<(PREP_TOT + 255) / 256, 256, 0, stream>>>(nf, W, nfh, Wh, deg);
    k_hist       <<<(NE + 255) / 256, 256, 0, stream>>>(ei, deg);
    k_blocksum   <<<NSCAN, 256, 0, stream>>>(deg, blocksum);
    k_scanfinal  <<<NSCAN, 256, 0, stream>>>(deg, blocksum, offsets, cursor);
    k_scatter_idx<<<(NE + 255) / 256, 256, 0, stream>>>(ei, cursor, sorted);
    k_aggregate  <<<(NN * 64 + 255) / 256, 256, 0, stream>>>((const unsigned*)nfh, sorted, offsets, (unsigned*)aggh);
    k_linear     <<<(NN + 63) / 64, 256, 0, stream>>>(aggh, Wh, b, out);
}